// Round 1
// baseline (860.525 us; speedup 1.0000x reference)
//
#include <hip/hip_runtime.h>

typedef unsigned short u16;
using short8 = __attribute__((ext_vector_type(8))) short;
using f32x4  = __attribute__((ext_vector_type(4))) float;

__device__ __forceinline__ u16 f2bf(float f) {
  union { float f; unsigned int u; } v; v.f = f;
  unsigned int u = v.u + 0x7FFFu + ((v.u >> 16) & 1u);
  return (u16)(u >> 16);
}

// ---------------- cast f32 -> bf16, 4 elems/thread ----------------
__global__ __launch_bounds__(256) void cast_f32_bf16(const float* __restrict__ in,
                                                     u16* __restrict__ out, int n4) {
  int i = blockIdx.x * 256 + threadIdx.x;
  if (i < n4) {
    float4 v = ((const float4*)in)[i];
    ushort4 o;
    o.x = f2bf(v.x); o.y = f2bf(v.y); o.z = f2bf(v.z); o.w = f2bf(v.w);
    ((ushort4*)out)[i] = o;
  }
}

// ---------------- NT GEMM: C[m,n] = sum_k A[m,k]*B[n,k] + bias[n] ----------------
// A: MxK bf16 row-major, B: NxK bf16 row-major. 128x128 block tile, BK=64,
// 4 waves in 2x2, each wave 64x64 via 4x4 tiles of 16x16x32 MFMA.
// XOR-swizzled LDS (16B chunk ^ (row&7)) to spread banks on ds_read_b128.
template<int OUT_F32>
__global__ __launch_bounds__(256) void gemm_nt_bias(
    const u16* __restrict__ A, const u16* __restrict__ B,
    const float* __restrict__ bias, void* __restrict__ Cout,
    int M, int N, int K)
{
  __shared__ u16 As[128 * 64];
  __shared__ u16 Bs[128 * 64];
  const int bn = blockIdx.x, bm = blockIdx.y;
  const int tid = threadIdx.x;
  const int wave = tid >> 6, lane = tid & 63, quad = lane >> 4, l16 = lane & 15;
  const int wm = wave >> 1, wn = wave & 1;

  const f32x4 z4 = {0.f, 0.f, 0.f, 0.f};
  f32x4 acc[4][4];
#pragma unroll
  for (int mt = 0; mt < 4; mt++)
#pragma unroll
    for (int nt = 0; nt < 4; nt++) acc[mt][nt] = z4;

  for (int k0 = 0; k0 < K; k0 += 64) {
    __syncthreads();
#pragma unroll
    for (int i = 0; i < 4; i++) {
      int cid = tid + i * 256, r = cid >> 3, c8 = cid & 7;
      int sw = r * 8 + (c8 ^ (r & 7));
      ((uint4*)As)[sw] = *(const uint4*)(A + (size_t)(bm * 128 + r) * K + k0 + c8 * 8);
      ((uint4*)Bs)[sw] = *(const uint4*)(B + (size_t)(bn * 128 + r) * K + k0 + c8 * 8);
    }
    __syncthreads();
#pragma unroll
    for (int ks = 0; ks < 2; ks++) {
      short8 af[4], bf[4];
#pragma unroll
      for (int mt = 0; mt < 4; mt++) {
        int row = wm * 64 + mt * 16 + l16;
        int chk = (ks * 4 + quad) ^ (row & 7);
        af[mt] = *(const short8*)((const short*)As + row * 64 + chk * 8);
      }
#pragma unroll
      for (int nt = 0; nt < 4; nt++) {
        int row = wn * 64 + nt * 16 + l16;
        int chk = (ks * 4 + quad) ^ (row & 7);
        bf[nt] = *(const short8*)((const short*)Bs + row * 64 + chk * 8);
      }
#pragma unroll
      for (int mt = 0; mt < 4; mt++)
#pragma unroll
        for (int nt = 0; nt < 4; nt++)
          acc[mt][nt] = __builtin_amdgcn_mfma_f32_16x16x32_bf16(af[mt], bf[nt], acc[mt][nt], 0, 0, 0);
    }
  }
#pragma unroll
  for (int mt = 0; mt < 4; mt++) {
    int row0 = bm * 128 + wm * 64 + mt * 16 + quad * 4;
#pragma unroll
    for (int nt = 0; nt < 4; nt++) {
      int col = bn * 128 + wn * 64 + nt * 16 + l16;
      float bv = bias[col];
#pragma unroll
      for (int r = 0; r < 4; r++) {
        float v = acc[mt][nt][r] + bv;
        if (OUT_F32) ((float*)Cout)[(size_t)(row0 + r) * N + col] = v;
        else         ((u16*)Cout)[(size_t)(row0 + r) * N + col] = f2bf(v);
      }
    }
  }
}

// ---------------- bf16 transpose: (B,2048,1024) -> (B,1024,2048) ----------------
__global__ __launch_bounds__(256) void transpose_bf16(const u16* __restrict__ in,
                                                      u16* __restrict__ out) {
  __shared__ u16 t[64][65];
  const int ct = blockIdx.x, rt = blockIdx.y, b = blockIdx.z;
  const u16* ip = in + (size_t)b * 2048 * 1024;
  u16* op = out + (size_t)b * 2048 * 1024;
#pragma unroll
  for (int i = 0; i < 16; i++) {
    int idx = threadIdx.x + i * 256; int r = idx >> 6, c = idx & 63;
    t[r][c] = ip[(size_t)(rt * 64 + r) * 1024 + ct * 64 + c];
  }
  __syncthreads();
#pragma unroll
  for (int i = 0; i < 16; i++) {
    int idx = threadIdx.x + i * 256; int r = idx >> 6, c = idx & 63;
    op[(size_t)(ct * 64 + r) * 2048 + rt * 64 + c] = t[c][r];
  }
}

// ---------------- fused causal attention ----------------
// Per block: one (b, h, 128-row q-block). Two sweeps over K-blocks (<= diagonal):
// sweep 1 accumulates row sumexp (no max-shift; scores clamped at 30 -> safe),
// sweep 2 writes normalized attn (fp32) + bf16 P to LDS, then PV MFMA.
__global__ __launch_bounds__(256) void attn_kernel(
    const u16* __restrict__ Qb, const u16* __restrict__ Kbuf,
    const u16* __restrict__ Vtb, float* __restrict__ attn,
    u16* __restrict__ ctx)
{
  __shared__ u16 Qs[128 * 64];    // [q][d]  16KB
  __shared__ u16 KVs[128 * 64];   // K: [k][d] / Vt: [d][k]  16KB
  __shared__ u16 Ps[128 * 128];   // bf16 P  32KB
  __shared__ float ls[128];
  __shared__ float rls[128];

  // load-balance swizzle: pair heavy (qb high) with light (qb low) across CUs
  const int flat = blockIdx.x;
  const int half = flat >> 8, r0 = flat & 255;
  const int bh = (half << 4) | (r0 >> 4);          // 0..31
  const int qb = half ? (15 - (r0 & 15)) : (r0 & 15);
  const int b = bh >> 4, h = bh & 15;

  const int tid = threadIdx.x;
  const int wave = tid >> 6, lane = tid & 63, quad = lane >> 4, l16 = lane & 15;
  const int wm = wave >> 1, wn = wave & 1;

  const int S = 2048, D = 1024;
  const u16* Qg = Qb  + ((size_t)b * S + qb * 128) * D + h * 64;
  const u16* Kg = Kbuf + (size_t)b * S * D + h * 64;
  const u16* Vg = Vtb + ((size_t)b * D + h * 64) * S;
  float* attng = attn + ((size_t)(b * 16 + h) * S + qb * 128) * S;

  const f32x4 z4 = {0.f, 0.f, 0.f, 0.f};
  const float SCALE = 0.125f;

#pragma unroll
  for (int i = 0; i < 4; i++) {
    int cid = tid + i * 256, r = cid >> 3, c8 = cid & 7;
    ((uint4*)Qs)[r * 8 + (c8 ^ (r & 7))] = *(const uint4*)(Qg + (size_t)r * D + c8 * 8);
  }
  if (tid < 128) ls[tid] = 0.f;

  // ---- sweep 1: row sums of exp ----
  for (int kb = 0; kb <= qb; kb++) {
    __syncthreads();
#pragma unroll
    for (int i = 0; i < 4; i++) {
      int cid = tid + i * 256, r = cid >> 3, c8 = cid & 7;
      ((uint4*)KVs)[r * 8 + (c8 ^ (r & 7))] =
          *(const uint4*)(Kg + (size_t)(kb * 128 + r) * D + c8 * 8);
    }
    __syncthreads();
    f32x4 acc[4][4];
#pragma unroll
    for (int mt = 0; mt < 4; mt++)
#pragma unroll
      for (int nt = 0; nt < 4; nt++) acc[mt][nt] = z4;
#pragma unroll
    for (int ks = 0; ks < 2; ks++) {
      short8 af[4], bf[4];
#pragma unroll
      for (int mt = 0; mt < 4; mt++) {
        int row = wm * 64 + mt * 16 + l16;
        int chk = (ks * 4 + quad) ^ (row & 7);
        af[mt] = *(const short8*)((const short*)Qs + row * 64 + chk * 8);
      }
#pragma unroll
      for (int nt = 0; nt < 4; nt++) {
        int row = wn * 64 + nt * 16 + l16;
        int chk = (ks * 4 + quad) ^ (row & 7);
        bf[nt] = *(const short8*)((const short*)KVs + row * 64 + chk * 8);
      }
#pragma unroll
      for (int mt = 0; mt < 4; mt++)
#pragma unroll
        for (int nt = 0; nt < 4; nt++)
          acc[mt][nt] = __builtin_amdgcn_mfma_f32_16x16x32_bf16(af[mt], bf[nt], acc[mt][nt], 0, 0, 0);
    }
#pragma unroll
    for (int mt = 0; mt < 4; mt++) {
#pragma unroll
      for (int rr = 0; rr < 4; rr++) {
        int row_local = wm * 64 + mt * 16 + quad * 4 + rr;
        int gq = qb * 128 + row_local;
        float psum = 0.f;
#pragma unroll
        for (int nt = 0; nt < 4; nt++) {
          int gk = kb * 128 + wn * 64 + nt * 16 + l16;
          float v = acc[mt][nt][rr] * SCALE;
          psum += (gk <= gq) ? __expf(fminf(v, 30.f)) : 0.f;
        }
        psum += __shfl_xor(psum, 1);
        psum += __shfl_xor(psum, 2);
        psum += __shfl_xor(psum, 4);
        psum += __shfl_xor(psum, 8);
        if (l16 == 0) atomicAdd(&ls[row_local], psum);
      }
    }
  }
  __syncthreads();
  if (tid < 128) rls[tid] = 1.0f / ls[tid];

  f32x4 cacc[2][4];
#pragma unroll
  for (int mt = 0; mt < 2; mt++)
#pragma unroll
    for (int nt = 0; nt < 4; nt++) cacc[mt][nt] = z4;

  // ---- sweep 2: attn values + PV ----
  for (int kb = 0; kb <= qb; kb++) {
    __syncthreads();
#pragma unroll
    for (int i = 0; i < 4; i++) {
      int cid = tid + i * 256, r = cid >> 3, c8 = cid & 7;
      ((uint4*)KVs)[r * 8 + (c8 ^ (r & 7))] =
          *(const uint4*)(Kg + (size_t)(kb * 128 + r) * D + c8 * 8);
    }
    __syncthreads();
    f32x4 acc[4][4];
#pragma unroll
    for (int mt = 0; mt < 4; mt++)
#pragma unroll
      for (int nt = 0; nt < 4; nt++) acc[mt][nt] = z4;
#pragma unroll
    for (int ks = 0; ks < 2; ks++) {
      short8 af[4], bf[4];
#pragma unroll
      for (int mt = 0; mt < 4; mt++) {
        int row = wm * 64 + mt * 16 + l16;
        int chk = (ks * 4 + quad) ^ (row & 7);
        af[mt] = *(const short8*)((const short*)Qs + row * 64 + chk * 8);
      }
#pragma unroll
      for (int nt = 0; nt < 4; nt++) {
        int row = wn * 64 + nt * 16 + l16;
        int chk = (ks * 4 + quad) ^ (row & 7);
        bf[nt] = *(const short8*)((const short*)KVs + row * 64 + chk * 8);
      }
#pragma unroll
      for (int mt = 0; mt < 4; mt++)
#pragma unroll
        for (int nt = 0; nt < 4; nt++)
          acc[mt][nt] = __builtin_amdgcn_mfma_f32_16x16x32_bf16(af[mt], bf[nt], acc[mt][nt], 0, 0, 0);
    }
    // normalized attn write + P into LDS
#pragma unroll
    for (int mt = 0; mt < 4; mt++) {
#pragma unroll
      for (int rr = 0; rr < 4; rr++) {
        int row_local = wm * 64 + mt * 16 + quad * 4 + rr;
        int gq = qb * 128 + row_local;
        float rl = rls[row_local];
#pragma unroll
        for (int nt = 0; nt < 4; nt++) {
          int colk = wn * 64 + nt * 16 + l16;
          int gk = kb * 128 + colk;
          float v = acc[mt][nt][rr] * SCALE;
          float p = (gk <= gq) ? __expf(fminf(v, 30.f)) * rl : 0.f;
          attng[(size_t)row_local * S + gk] = p;
          Ps[row_local * 128 + (((colk >> 3) ^ (row_local & 7)) << 3) + (colk & 7)] = f2bf(p);
        }
      }
    }
    __syncthreads();
    // stage Vt tile [d=64][k=128]
#pragma unroll
    for (int i = 0; i < 4; i++) {
      int cid = tid + i * 256, r = cid >> 4, c8 = cid & 15;
      ((uint4*)KVs)[r * 16 + (c8 ^ (r & 7))] =
          *(const uint4*)(Vg + (size_t)r * S + kb * 128 + c8 * 8);
    }
    __syncthreads();
    // PV: each wave 32 rows x 64 cols
#pragma unroll
    for (int ks = 0; ks < 4; ks++) {
      short8 pf[2], vf[4];
#pragma unroll
      for (int mt = 0; mt < 2; mt++) {
        int row = wave * 32 + mt * 16 + l16;
        int chk = (ks * 4 + quad) ^ (row & 7);
        pf[mt] = *(const short8*)((const short*)Ps + row * 128 + chk * 8);
      }
#pragma unroll
      for (int nt = 0; nt < 4; nt++) {
        int row = nt * 16 + l16;
        int chk = (ks * 4 + quad) ^ (row & 7);
        vf[nt] = *(const short8*)((const short*)KVs + row * 128 + chk * 8);
      }
#pragma unroll
      for (int mt = 0; mt < 2; mt++)
#pragma unroll
        for (int nt = 0; nt < 4; nt++)
          cacc[mt][nt] = __builtin_amdgcn_mfma_f32_16x16x32_bf16(pf[mt], vf[nt], cacc[mt][nt], 0, 0, 0);
    }
  }

  // zero-fill strictly-upper k-blocks of attn
  {
    int kstart = (qb + 1) * 128;
    for (int rr = 0; rr < 128; rr++) {
      float* rowp = attng + (size_t)rr * S;
      for (int c = kstart + tid * 4; c < S; c += 1024)
        *(float4*)(rowp + c) = make_float4(0.f, 0.f, 0.f, 0.f);
    }
  }

  // ctx write (bf16, (B,S,D) layout)
#pragma unroll
  for (int mt = 0; mt < 2; mt++)
#pragma unroll
    for (int nt = 0; nt < 4; nt++)
#pragma unroll
      for (int rr = 0; rr < 4; rr++) {
        int row_local = wave * 32 + mt * 16 + quad * 4 + rr;
        int col = nt * 16 + l16;
        ctx[((size_t)b * S + qb * 128 + row_local) * D + h * 64 + col] = f2bf(cacc[mt][nt][rr]);
      }
}

extern "C" void kernel_launch(void* const* d_in, const int* in_sizes, int n_in,
                              void* d_out, int out_size, void* d_ws, size_t ws_size,
                              hipStream_t stream) {
  const float* x  = (const float*)d_in[0];
  const float* Wq = (const float*)d_in[1];
  const float* bq = (const float*)d_in[2];
  const float* Wk = (const float*)d_in[3];
  const float* bk = (const float*)d_in[4];
  const float* Wv = (const float*)d_in[5];
  const float* bv = (const float*)d_in[6];
  const float* Wo = (const float*)d_in[7];
  const float* bo = (const float*)d_in[8];

  float* out_f32  = (float*)d_out;              // (B,S,D) fp32
  float* attn_out = (float*)d_out + 4194304;    // (B,H,S,S) fp32

  char* w = (char*)d_ws;
  u16* xb   = (u16*)(w + 0);          // 8 MB
  u16* Wqb  = (u16*)(w + 8388608);    // 2 MB
  u16* Wkb  = (u16*)(w + 10485760);
  u16* Wvb  = (u16*)(w + 12582912);
  u16* Wob  = (u16*)(w + 14680064);
  u16* Qbuf = (u16*)(w + 16777216);   // 8 MB each
  u16* Kbuf = (u16*)(w + 25165824);
  u16* Vbuf = (u16*)(w + 33554432);
  u16* Vtb  = (u16*)(w + 41943040);
  u16* ctxb = (u16*)(w + 50331648);   // ends at 56 MB

  cast_f32_bf16<<<4096, 256, 0, stream>>>(x,  xb,  1048576);
  cast_f32_bf16<<<1024, 256, 0, stream>>>(Wq, Wqb, 262144);
  cast_f32_bf16<<<1024, 256, 0, stream>>>(Wk, Wkb, 262144);
  cast_f32_bf16<<<1024, 256, 0, stream>>>(Wv, Wvb, 262144);
  cast_f32_bf16<<<1024, 256, 0, stream>>>(Wo, Wob, 262144);

  gemm_nt_bias<0><<<dim3(8, 32), 256, 0, stream>>>(xb, Wqb, bq, Qbuf, 4096, 1024, 1024);
  gemm_nt_bias<0><<<dim3(8, 32), 256, 0, stream>>>(xb, Wkb, bk, Kbuf, 4096, 1024, 1024);
  gemm_nt_bias<0><<<dim3(8, 32), 256, 0, stream>>>(xb, Wvb, bv, Vbuf, 4096, 1024, 1024);

  transpose_bf16<<<dim3(16, 32, 2), 256, 0, stream>>>(Vbuf, Vtb);

  attn_kernel<<<512, 256, 0, stream>>>(Qbuf, Kbuf, Vtb, attn_out, ctxb);

  gemm_nt_bias<1><<<dim3(8, 32), 256, 0, stream>>>(ctxb, Wob, bo, out_f32, 4096, 1024, 1024);
}

// Round 3
// 804.519 us; speedup vs baseline: 1.0696x; 1.0696x over previous
//
#include <hip/hip_runtime.h>

typedef unsigned short u16;
using short8 = __attribute__((ext_vector_type(8))) short;
using f32x4  = __attribute__((ext_vector_type(4))) float;
using u16x4  = __attribute__((ext_vector_type(4))) unsigned short;

__device__ __forceinline__ u16 f2bf(float f) {
  union { float f; unsigned int u; } v; v.f = f;
  unsigned int u = v.u + 0x7FFFu + ((v.u >> 16) & 1u);
  return (u16)(u >> 16);
}
__device__ __forceinline__ float bf2f(u16 u) {
  union { unsigned int u; float f; } v; v.u = ((unsigned int)u) << 16;
  return v.f;
}
// async global->LDS, 16B per lane. LDS dest = wave-uniform base + lane*16.
__device__ __forceinline__ void glds16(const void* g, void* l) {
  __builtin_amdgcn_global_load_lds(
      (const __attribute__((address_space(1))) void*)g,
      (__attribute__((address_space(3))) void*)l, 16, 0, 0);
}

// ---------------- merged f32 -> bf16 casts ----------------
// x: 1048576 float4 (B*S*D = 4,194,304 floats); each W: 262144 float4.
// Total 2,097,152 float4 -> 8192 blocks x 256.
__global__ __launch_bounds__(256) void cast_all(
    const float* __restrict__ x, const float* __restrict__ wq,
    const float* __restrict__ wk, const float* __restrict__ wv,
    const float* __restrict__ wo,
    u16* __restrict__ xb, u16* __restrict__ wqb, u16* __restrict__ wkb,
    u16* __restrict__ wvb, u16* __restrict__ wob) {
  int i = blockIdx.x * 256 + threadIdx.x;
  const float4* src; ushort4* dst; int off;
  if (i < 1048576)      { src = (const float4*)x;  dst = (ushort4*)xb;  off = i; }
  else if (i < 1310720) { src = (const float4*)wq; dst = (ushort4*)wqb; off = i - 1048576; }
  else if (i < 1572864) { src = (const float4*)wk; dst = (ushort4*)wkb; off = i - 1310720; }
  else if (i < 1835008) { src = (const float4*)wv; dst = (ushort4*)wvb; off = i - 1572864; }
  else                  { src = (const float4*)wo; dst = (ushort4*)wob; off = i - 1835008; }
  float4 v = src[off];
  ushort4 o;
  o.x = f2bf(v.x); o.y = f2bf(v.y); o.z = f2bf(v.z); o.w = f2bf(v.w);
  dst[off] = o;
}

// ---------------- NT GEMM with global_load_lds staging ----------------
// C[m,n] = sum_k A[m,k]*B[n,k] + bias[n]. 128x128 tile, BK=64.
// Source-XOR swizzle: LDS[row][c] holds global chunk c^(row&7) -> frag reads
// use chk=(ks*4+quad)^(row&7), conflict-free, while glds dest stays linear.
// Fused over up to 3 weight matrices: sel = bn>>3.
template<int OUT_F32>
__global__ __launch_bounds__(256) void gemm_nt_glds(
    const u16* __restrict__ A,
    const u16* __restrict__ B0, const u16* __restrict__ B1, const u16* __restrict__ B2,
    const float* __restrict__ bias0, const float* __restrict__ bias1, const float* __restrict__ bias2,
    void* __restrict__ C0, void* __restrict__ C1, void* __restrict__ C2,
    int K)
{
  __shared__ u16 As[128 * 64];
  __shared__ u16 Bs[128 * 64];
  const int bn = blockIdx.x, bm = blockIdx.y;
  const int sel = bn >> 3, bnl = bn & 7;
  const u16* B = sel == 0 ? B0 : (sel == 1 ? B1 : B2);
  const float* bias = sel == 0 ? bias0 : (sel == 1 ? bias1 : bias2);
  void* C = sel == 0 ? C0 : (sel == 1 ? C1 : C2);

  const int tid = threadIdx.x;
  const int w = tid >> 6, lane = tid & 63, quad = lane >> 4, l16 = lane & 15;
  const int wm = w >> 1, wn = w & 1;
  const int srow = lane >> 3, gc = (lane & 7) ^ srow;

  const u16* aseg = A + (size_t)(bm * 128 + w * 32 + srow) * K + gc * 8;
  const u16* bseg = B + (size_t)(bnl * 128 + w * 32 + srow) * K + gc * 8;

  const f32x4 z4 = {0.f, 0.f, 0.f, 0.f};
  f32x4 acc[4][4];
#pragma unroll
  for (int mt = 0; mt < 4; mt++)
#pragma unroll
    for (int nt = 0; nt < 4; nt++) acc[mt][nt] = z4;

  for (int k0 = 0; k0 < K; k0 += 64) {
    __syncthreads();
#pragma unroll
    for (int j = 0; j < 4; j++) {
      glds16(aseg + (size_t)(j * 8) * K + k0, (u16*)As + (w * 4 + j) * 512);
      glds16(bseg + (size_t)(j * 8) * K + k0, (u16*)Bs + (w * 4 + j) * 512);
    }
    __syncthreads();
#pragma unroll
    for (int ks = 0; ks < 2; ks++) {
      short8 af[4], bf[4];
#pragma unroll
      for (int mt = 0; mt < 4; mt++) {
        int row = wm * 64 + mt * 16 + l16;
        int chk = (ks * 4 + quad) ^ (row & 7);
        af[mt] = *(const short8*)((const short*)As + row * 64 + chk * 8);
      }
#pragma unroll
      for (int nt = 0; nt < 4; nt++) {
        int row = wn * 64 + nt * 16 + l16;
        int chk = (ks * 4 + quad) ^ (row & 7);
        bf[nt] = *(const short8*)((const short*)Bs + row * 64 + chk * 8);
      }
#pragma unroll
      for (int mt = 0; mt < 4; mt++)
#pragma unroll
        for (int nt = 0; nt < 4; nt++)
          acc[mt][nt] = __builtin_amdgcn_mfma_f32_16x16x32_bf16(af[mt], bf[nt], acc[mt][nt], 0, 0, 0);
    }
  }
#pragma unroll
  for (int mt = 0; mt < 4; mt++) {
    int row0 = bm * 128 + wm * 64 + mt * 16 + quad * 4;
#pragma unroll
    for (int nt = 0; nt < 4; nt++) {
      int col = bnl * 128 + wn * 64 + nt * 16 + l16;
      float bv = bias[col];
#pragma unroll
      for (int r = 0; r < 4; r++) {
        float v = acc[mt][nt][r] + bv;
        if (OUT_F32) ((float*)C)[(size_t)(row0 + r) * 1024 + col] = v;
        else         ((u16*)C)[(size_t)(row0 + r) * 1024 + col] = f2bf(v);
      }
    }
  }
}

// ---------------- bf16 transpose: (B,2048,1024) -> (B,1024,2048) ----------------
__global__ __launch_bounds__(256) void transpose_bf16(const u16* __restrict__ in,
                                                      u16* __restrict__ out) {
  __shared__ u16 t[64][65];
  const int ct = blockIdx.x, rt = blockIdx.y, b = blockIdx.z;
  const u16* ip = in + (size_t)b * 2048 * 1024;
  u16* op = out + (size_t)b * 2048 * 1024;
#pragma unroll
  for (int i = 0; i < 16; i++) {
    int idx = threadIdx.x + i * 256; int r = idx >> 6, c = idx & 63;
    t[r][c] = ip[(size_t)(rt * 64 + r) * 1024 + ct * 64 + c];
  }
  __syncthreads();
#pragma unroll
  for (int i = 0; i < 16; i++) {
    int idx = threadIdx.x + i * 256; int r = idx >> 6, c = idx & 63;
    op[(size_t)(ct * 64 + r) * 2048 + rt * 64 + c] = t[c][r];
  }
}

// ---------------- fused causal attention ----------------
__global__ __launch_bounds__(256) void attn_kernel(
    const u16* __restrict__ Qb, const u16* __restrict__ Kbuf,
    const u16* __restrict__ Vtb, float* __restrict__ attn,
    u16* __restrict__ ctx)
{
  __shared__ u16 Qs[128 * 64];
  __shared__ u16 KVs[128 * 64];   // K tile [k][d] / Vt tile [d][k]
  __shared__ u16 Ps[128 * 128];
  __shared__ float ls[128];
  __shared__ float rls[128];

  const int flat = blockIdx.x;
  const int half = flat >> 8, r0 = flat & 255;
  const int bh = (half << 4) | (r0 >> 4);
  const int qb = half ? (15 - (r0 & 15)) : (r0 & 15);
  const int b = bh >> 4, h = bh & 15;

  const int tid = threadIdx.x;
  const int w = tid >> 6, lane = tid & 63, quad = lane >> 4, l16 = lane & 15;
  const int wm = w >> 1, wn = w & 1;
  const int srow8 = lane >> 3, gc8 = (lane & 7) ^ srow8;
  const int srow16 = lane >> 4, sc16 = lane & 15;

  const int S = 2048, D = 1024;
  const u16* Qg = Qb + ((size_t)b * S + qb * 128) * D + h * 64;
  const u16* Kg = Kbuf + (size_t)b * S * D + h * 64;
  const u16* Vg = Vtb + ((size_t)b * D + h * 64) * S;
  float* attng = attn + ((size_t)(b * 16 + h) * S + qb * 128) * S;

  const float SCALE = 0.125f;
  const f32x4 z4 = {0.f, 0.f, 0.f, 0.f};

  // stage Q once (async; first barrier below drains vmcnt)
#pragma unroll
  for (int j = 0; j < 4; j++)
    glds16(Qg + (size_t)(w * 32 + j * 8 + srow8) * D + gc8 * 8, (u16*)Qs + (w * 4 + j) * 512);
  if (tid < 128) ls[tid] = 0.f;

  // ---- sweep 1: row sums of exp ----
  for (int kb = 0; kb <= qb; kb++) {
    __syncthreads();
#pragma unroll
    for (int j = 0; j < 4; j++)
      glds16(Kg + (size_t)(kb * 128 + w * 32 + j * 8 + srow8) * D + gc8 * 8,
             (u16*)KVs + (w * 4 + j) * 512);
    __syncthreads();
    f32x4 acc[4][4];
#pragma unroll
    for (int mt = 0; mt < 4; mt++)
#pragma unroll
      for (int nt = 0; nt < 4; nt++) acc[mt][nt] = z4;
#pragma unroll
    for (int ks = 0; ks < 2; ks++) {
      short8 af[4], bf[4];
#pragma unroll
      for (int mt = 0; mt < 4; mt++) {
        int row = wm * 64 + mt * 16 + l16;
        int chk = (ks * 4 + quad) ^ (row & 7);
        af[mt] = *(const short8*)((const short*)Qs + row * 64 + chk * 8);
      }
#pragma unroll
      for (int nt = 0; nt < 4; nt++) {
        int row = wn * 64 + nt * 16 + l16;
        int chk = (ks * 4 + quad) ^ (row & 7);
        bf[nt] = *(const short8*)((const short*)KVs + row * 64 + chk * 8);
      }
#pragma unroll
      for (int mt = 0; mt < 4; mt++)
#pragma unroll
        for (int nt = 0; nt < 4; nt++)
          acc[mt][nt] = __builtin_amdgcn_mfma_f32_16x16x32_bf16(af[mt], bf[nt], acc[mt][nt], 0, 0, 0);
    }
#pragma unroll
    for (int mt = 0; mt < 4; mt++) {
#pragma unroll
      for (int rr = 0; rr < 4; rr++) {
        int row_local = wm * 64 + mt * 16 + quad * 4 + rr;
        int gq = qb * 128 + row_local;
        float psum = 0.f;
#pragma unroll
        for (int nt = 0; nt < 4; nt++) {
          int gk = kb * 128 + wn * 64 + nt * 16 + l16;
          float v = acc[mt][nt][rr] * SCALE;
          psum += (gk <= gq) ? __expf(fminf(v, 30.f)) : 0.f;
        }
        psum += __shfl_xor(psum, 1);
        psum += __shfl_xor(psum, 2);
        psum += __shfl_xor(psum, 4);
        psum += __shfl_xor(psum, 8);
        if (l16 == 0) atomicAdd(&ls[row_local], psum);
      }
    }
  }
  __syncthreads();
  if (tid < 128) rls[tid] = 1.0f / ls[tid];

  f32x4 cacc[2][4];
#pragma unroll
  for (int mt = 0; mt < 2; mt++)
#pragma unroll
    for (int nt = 0; nt < 4; nt++) cacc[mt][nt] = z4;

  // ---- sweep 2: attn values + PV ----
  for (int kb = 0; kb <= qb; kb++) {
    __syncthreads();
#pragma unroll
    for (int j = 0; j < 4; j++)
      glds16(Kg + (size_t)(kb * 128 + w * 32 + j * 8 + srow8) * D + gc8 * 8,
             (u16*)KVs + (w * 4 + j) * 512);
    __syncthreads();
    f32x4 acc[4][4];
#pragma unroll
    for (int mt = 0; mt < 4; mt++)
#pragma unroll
      for (int nt = 0; nt < 4; nt++) acc[mt][nt] = z4;
#pragma unroll
    for (int ks = 0; ks < 2; ks++) {
      short8 af[4], bf[4];
#pragma unroll
      for (int mt = 0; mt < 4; mt++) {
        int row = wm * 64 + mt * 16 + l16;
        int chk = (ks * 4 + quad) ^ (row & 7);
        af[mt] = *(const short8*)((const short*)Qs + row * 64 + chk * 8);
      }
#pragma unroll
      for (int nt = 0; nt < 4; nt++) {
        int row = wn * 64 + nt * 16 + l16;
        int chk = (ks * 4 + quad) ^ (row & 7);
        bf[nt] = *(const short8*)((const short*)KVs + row * 64 + chk * 8);
      }
#pragma unroll
      for (int mt = 0; mt < 4; mt++)
#pragma unroll
        for (int nt = 0; nt < 4; nt++)
          acc[mt][nt] = __builtin_amdgcn_mfma_f32_16x16x32_bf16(af[mt], bf[nt], acc[mt][nt], 0, 0, 0);
    }
    // epilogue: P -> Ps (bf16, XOR-swizzled rows)
#pragma unroll
    for (int mt = 0; mt < 4; mt++) {
#pragma unroll
      for (int rr = 0; rr < 4; rr++) {
        int row_local = wm * 64 + mt * 16 + quad * 4 + rr;
        int gq = qb * 128 + row_local;
        float rl = rls[row_local];
#pragma unroll
        for (int nt = 0; nt < 4; nt++) {
          int colk = wn * 64 + nt * 16 + l16;
          int gk = kb * 128 + colk;
          float v = acc[mt][nt][rr] * SCALE;
          float p = (gk <= gq) ? __expf(fminf(v, 30.f)) * rl : 0.f;
          Ps[row_local * 128 + (((colk >> 3) ^ (row_local & 7)) << 3) + (colk & 7)] = f2bf(p);
        }
      }
    }
    __syncthreads();  // Ps ready; all waves done reading K from KVs
    // stage Vt tile [d=64][k=128] async into KVs
#pragma unroll
    for (int j = 0; j < 4; j++) {
      int r0v = (w * 4 + j) * 4;
      int row = r0v + srow16;
      int gcv = sc16 ^ (row & 7);
      glds16(Vg + (size_t)row * S + kb * 128 + gcv * 8, (u16*)KVs + r0v * 128);
    }
    // attn write from Ps: coalesced NT dwordx4 (overlaps Vt load latency)
#pragma unroll
    for (int s = 0; s < 16; s++) {
      int e4 = s * 256 + tid;
      int row = e4 >> 5, col = (e4 & 31) * 4;
      int chunk = (col >> 3) ^ (row & 7);
      u16x4 pv = *(const u16x4*)((const u16*)Ps + row * 128 + chunk * 8 + (col & 7));
      f32x4 o;
      o[0] = bf2f(pv[0]); o[1] = bf2f(pv[1]); o[2] = bf2f(pv[2]); o[3] = bf2f(pv[3]);
      __builtin_nontemporal_store(o, (f32x4*)(attng + (size_t)row * S + kb * 128 + col));
    }
    __syncthreads();  // Vt ready
    // PV: each wave 32 rows x 64 cols
#pragma unroll
    for (int ks = 0; ks < 4; ks++) {
      short8 pf[2], vf[4];
#pragma unroll
      for (int mt = 0; mt < 2; mt++) {
        int row = w * 32 + mt * 16 + l16;
        int chk = (ks * 4 + quad) ^ (row & 7);
        pf[mt] = *(const short8*)((const short*)Ps + row * 128 + chk * 8);
      }
#pragma unroll
      for (int nt = 0; nt < 4; nt++) {
        int row = nt * 16 + l16;
        int chk = (ks * 4 + quad) ^ (row & 7);
        vf[nt] = *(const short8*)((const short*)KVs + row * 128 + chk * 8);
      }
#pragma unroll
      for (int mt = 0; mt < 2; mt++)
#pragma unroll
        for (int nt = 0; nt < 4; nt++)
          cacc[mt][nt] = __builtin_amdgcn_mfma_f32_16x16x32_bf16(pf[mt], vf[nt], cacc[mt][nt], 0, 0, 0);
    }
  }

  // zero-fill strictly-upper k-blocks of attn (NT)
  {
    int kstart = (qb + 1) * 128;
    const f32x4 zz = {0.f, 0.f, 0.f, 0.f};
    for (int rr = 0; rr < 128; rr++) {
      float* rowp = attng + (size_t)rr * S;
      for (int c = kstart + tid * 4; c < S; c += 1024)
        __builtin_nontemporal_store(zz, (f32x4*)(rowp + c));
    }
  }

  // ctx write (bf16, (B,S,D) layout)
#pragma unroll
  for (int mt = 0; mt < 2; mt++)
#pragma unroll
    for (int nt = 0; nt < 4; nt++)
#pragma unroll
      for (int rr = 0; rr < 4; rr++) {
        int row_local = w * 32 + mt * 16 + quad * 4 + rr;
        int col = nt * 16 + l16;
        ctx[((size_t)b * S + qb * 128 + row_local) * D + h * 64 + col] = f2bf(cacc[mt][nt][rr]);
      }
}

extern "C" void kernel_launch(void* const* d_in, const int* in_sizes, int n_in,
                              void* d_out, int out_size, void* d_ws, size_t ws_size,
                              hipStream_t stream) {
  const float* x  = (const float*)d_in[0];
  const float* Wq = (const float*)d_in[1];
  const float* bq = (const float*)d_in[2];
  const float* Wk = (const float*)d_in[3];
  const float* bk = (const float*)d_in[4];
  const float* Wv = (const float*)d_in[5];
  const float* bv = (const float*)d_in[6];
  const float* Wo = (const float*)d_in[7];
  const float* bo = (const float*)d_in[8];

  float* out_f32  = (float*)d_out;              // (B,S,D) fp32
  float* attn_out = (float*)d_out + 4194304;    // (B,H,S,S) fp32

  char* w = (char*)d_ws;
  u16* xb   = (u16*)(w + 0);
  u16* Wqb  = (u16*)(w + 8388608);
  u16* Wkb  = (u16*)(w + 10485760);
  u16* Wvb  = (u16*)(w + 12582912);
  u16* Wob  = (u16*)(w + 14680064);
  u16* Qbuf = (u16*)(w + 16777216);
  u16* Kbuf = (u16*)(w + 25165824);
  u16* Vbuf = (u16*)(w + 33554432);
  u16* Vtb  = (u16*)(w + 41943040);
  u16* ctxb = (u16*)(w + 50331648);

  cast_all<<<8192, 256, 0, stream>>>(x, Wq, Wk, Wv, Wo, xb, Wqb, Wkb, Wvb, Wob);

  gemm_nt_glds<0><<<dim3(24, 32), 256, 0, stream>>>(
      xb, Wqb, Wkb, Wvb, bq, bk, bv, Qbuf, Kbuf, Vbuf, 1024);

  transpose_bf16<<<dim3(16, 32, 2), 256, 0, stream>>>(Vbuf, Vtb);

  attn_kernel<<<512, 256, 0, stream>>>(Qbuf, Kbuf, Vtb, attn_out, ctxb);

  gemm_nt_glds<1><<<dim3(8, 32), 256, 0, stream>>>(
      ctxb, Wob, Wob, Wob, bo, bo, bo, out_f32, out_f32, out_f32, 1024);
}